// Round 13
// baseline (97.194 us; speedup 1.0000x reference)
//
#include <hip/hip_runtime.h>
#include <hip/hip_bf16.h>
#include <math.h>

#define BN_EPS 1e-5f
#define B_  96
#define N_  20
#define D_  2048
#define K_  10
#define M_  (B_*N_)   // 1920
#define R_  (2*D_)    // 4096

typedef __attribute__((ext_vector_type(8))) short bf16x8;
typedef __attribute__((ext_vector_type(4))) float f32x4;
typedef __attribute__((ext_vector_type(8))) unsigned short ushort8;

static __device__ __forceinline__ unsigned short f2bf(float f) {
  unsigned int u = __builtin_bit_cast(unsigned int, f);
  u = u + 0x7fffu + ((u >> 16) & 1u);   // RNE (finite inputs only)
  return (unsigned short)(u >> 16);
}

#define GLOAD_LDS16(g, l) \
  __builtin_amdgcn_global_load_lds((const __attribute__((address_space(1))) void*)(g), \
                                   (__attribute__((address_space(3))) void*)(l), 16, 0, 0)

// ------- kernel 1: heterogeneous prep --------------------------------------
// blocks 0..95: knn (one-pass m-streaming, round-12) + cast x->bf16.
// blocks 96..607: cast_w with EXACT 4-chunk-per-thread unroll: 8 float4 loads
// in flight per thread (round-12 lesson: grid-stride 1-chunk loop was
// latency-bound at ~900 GB/s; 4x outstanding bytes targets HBM saturation).
__global__ __launch_bounds__(512, 2) void prep_kernel(const float* __restrict__ x,
                                                      const float* __restrict__ cw,
                                                      int* __restrict__ nn_idx,
                                                      unsigned short* __restrict__ Xb,
                                                      unsigned short* __restrict__ Wn)
{
  int t = threadIdx.x;
  if (blockIdx.x >= B_) {
    // Wn[r][k], r=2*o+h: h=0 -> cw[o][k], h=1 -> cw[o][2048+k].
    // 1,048,576 chunks = 512 blocks * 512 threads * 4 chunks (exact).
    int i0 = (blockIdx.x - B_) * 512 + t;        // + q*262144, q=0..3
    auto srcp = [&](int i) {
      int r = i >> 8, k = (i & 255) * 8;
      return cw + (size_t)(r >> 1) * R_ + ((r & 1) << 11) + k;
    };
    const float* s0 = srcp(i0);
    const float* s1 = srcp(i0 + 262144);
    const float* s2 = srcp(i0 + 524288);
    const float* s3 = srcp(i0 + 786432);
    float4 a0 = *(const float4*)s0, c0 = *(const float4*)(s0 + 4);
    float4 a1 = *(const float4*)s1, c1 = *(const float4*)(s1 + 4);
    float4 a2 = *(const float4*)s2, c2 = *(const float4*)(s2 + 4);
    float4 a3 = *(const float4*)s3, c3 = *(const float4*)(s3 + 4);
    ushort8 o0 = { f2bf(a0.x), f2bf(a0.y), f2bf(a0.z), f2bf(a0.w),
                   f2bf(c0.x), f2bf(c0.y), f2bf(c0.z), f2bf(c0.w) };
    ushort8 o1 = { f2bf(a1.x), f2bf(a1.y), f2bf(a1.z), f2bf(a1.w),
                   f2bf(c1.x), f2bf(c1.y), f2bf(c1.z), f2bf(c1.w) };
    ushort8 o2 = { f2bf(a2.x), f2bf(a2.y), f2bf(a2.z), f2bf(a2.w),
                   f2bf(c2.x), f2bf(c2.y), f2bf(c2.z), f2bf(c2.w) };
    ushort8 o3 = { f2bf(a3.x), f2bf(a3.y), f2bf(a3.z), f2bf(a3.w),
                   f2bf(c3.x), f2bf(c3.y), f2bf(c3.z), f2bf(c3.w) };
    *((ushort8*)Wn + i0)          = o0;
    *((ushort8*)Wn + i0 + 262144) = o1;
    *((ushort8*)Wn + i0 + 524288) = o2;
    *((ushort8*)Wn + i0 + 786432) = o3;
    return;
  }
  // ---- knn part (round-12 one-pass, proven) ----
  int b = blockIdx.x, w = t >> 6, lane = t & 63;
  __shared__ float innr[N_*N_];
  __shared__ float adjl[N_*N_];
  const float* xb = x + (size_t)b * N_ * D_;
  int n1 = w, n2 = w + 8, n3 = (w < 4) ? 16 + w : -1;
  float4 c1[8], c2[8], c3[8];
  const float4* p1 = (const float4*)(xb + n1 * D_);
  const float4* p2 = (const float4*)(xb + n2 * D_);
  #pragma unroll
  for (int j = 0; j < 8; ++j) { c1[j] = p1[lane + 64*j]; c2[j] = p2[lane + 64*j]; }
  if (n3 >= 0) {
    const float4* p3 = (const float4*)(xb + n3 * D_);
    #pragma unroll
    for (int j = 0; j < 8; ++j) c3[j] = p3[lane + 64*j];
  }
  for (int m = n1; m < N_; ++m) {                // each m-row streamed ONCE
    bool d2 = (m >= n2), d3 = (n3 >= 0) && (m >= n3);   // wave-uniform
    const float4* pm = (const float4*)(xb + m * D_);
    float s1 = 0.f, s2 = 0.f, s3 = 0.f;
    #pragma unroll
    for (int j = 0; j < 8; ++j) {
      float4 v = pm[lane + 64*j];
      s1 = fmaf(c1[j].x, v.x, fmaf(c1[j].y, v.y, fmaf(c1[j].z, v.z, fmaf(c1[j].w, v.w, s1))));
      if (d2) s2 = fmaf(c2[j].x, v.x, fmaf(c2[j].y, v.y, fmaf(c2[j].z, v.z, fmaf(c2[j].w, v.w, s2))));
      if (d3) s3 = fmaf(c3[j].x, v.x, fmaf(c3[j].y, v.y, fmaf(c3[j].z, v.z, fmaf(c3[j].w, v.w, s3))));
    }
    #pragma unroll
    for (int off = 32; off > 0; off >>= 1) {
      s1 += __shfl_xor(s1, off, 64);
      if (d2) s2 += __shfl_xor(s2, off, 64);
      if (d3) s3 += __shfl_xor(s3, off, 64);
    }
    if (lane == 0) {
      innr[n1*N_+m] = s1; innr[m*N_+n1] = s1;
      if (d2) { innr[n2*N_+m] = s2; innr[m*N_+n2] = s2; }
      if (d3) { innr[n3*N_+m] = s3; innr[m*N_+n3] = s3; }
    }
  }
  __syncthreads();
  for (int p = t; p < N_*N_; p += 512) {
    int n = p / N_, m = p % N_;
    adjl[p] = innr[n*N_+n] + innr[m*N_+m] - 2.f * innr[p];
  }
  __syncthreads();
  if (t < N_) {
    int n = t;
    unsigned mask = 0;
    for (int it = 0; it < K_; ++it) {
      float bv = INFINITY; int bi = 0;
      for (int m = 0; m < N_; ++m) {
        if (!((mask >> m) & 1u)) {
          float v = adjl[n*N_+m];
          if (v < bv) { bv = v; bi = m; }
        }
      }
      mask |= 1u << bi;
      nn_idx[(b*N_ + n)*K_ + it] = bi;
    }
  }
  // fused cast of this batch's x slice -> bf16
  unsigned short* xo = Xb + (size_t)b * N_ * D_;
  for (int i = t; i < N_*D_/8; i += 512) {
    const float4* src = (const float4*)xb + (size_t)i * 2;
    float4 a = src[0], c = src[1];
    ushort8 o = { f2bf(a.x), f2bf(a.y), f2bf(a.z), f2bf(a.w),
                  f2bf(c.x), f2bf(c.y), f2bf(c.z), f2bf(c.w) };
    *((ushort8*)xo + i) = o;
  }
}

// ---------------- kernel 2: fused bf16 MFMA GEMM + BN/ReLU/neighbor-max ----
// 80x128 tile, BK=64, 4 waves, grid 24x32=768, 3 blocks/CU.
// ROUND-13 CHANGE: B fragments load GLOBAL->REGISTER directly (each wave owns
// distinct B rows -> no cross-wave redundancy); only A (shared by all 4 waves)
// stays LDS-staged with the 3-bit XOR swizzle. Cuts block LDS traffic 39%
// (round-12 diagnosis: K-loop is LDS-BW-bound at ~77 of ~85 B/cyc).
// Schedule = round-6 proven 2-step: stage/loadB(next) -> compute(cur) -> sync.
__global__ __launch_bounds__(256, 3) void fused_gemm(
    const unsigned short* __restrict__ Xb, const unsigned short* __restrict__ Wn,
    const int* __restrict__ nn_idx, const float* __restrict__ conv_b,
    const float* __restrict__ gamma, const float* __restrict__ beta,
    const float* __restrict__ mean, const float* __restrict__ var,
    float* __restrict__ out)
{
  __shared__ __align__(16) char smem[44160];
  // A buffer sel at smem + sel*10240: [80][64] bf16, 10240 B each
  float* Cl  = (float*)smem;                    // [80][128] f32, 40960 B (epilogue reuse)
  int*   idxl = (int*)(smem + 40960);           // [4][200] int, 3200 B — loaded post-loop

  // bijective XCD-chunk swizzle (768 % 8 == 0)
  int flat = blockIdx.y * 24 + blockIdx.x;
  int nf = (flat & 7) * 96 + (flat >> 3);
  int bx = nf % 24, by = nf / 24;

  int t = threadIdx.x, lane = t & 63, w = t >> 6;  // w = wr (0..3)
  int m0 = bx * 80, b0 = bx * 4;
  int r0 = by * 128, o0 = by * 64;
  int rowsel = lane & 15, ksel = lane >> 4;

  f32x4 acc[5][2] = {};

  // per-lane B base: row r0 + w*32 + rowsel, col chunk ksel*8
  const unsigned short* wnBase = Wn + (size_t)(r0 + w*32 + rowsel) * D_ + ksel*8;

  auto stageA = [&](int sel, int k0) {
    unsigned short* Asb = (unsigned short*)(smem + sel*10240);
    #pragma unroll
    for (int i = 0; i < 3; ++i) {                 // A: 640 16B-chunks
      int fl = i*256 + t;
      if (fl < 640) {
        int row = fl >> 3, kc = fl & 7;
        GLOAD_LDS16(Xb + (size_t)(m0 + row) * D_ + k0 + ((kc ^ (row & 7)) << 3),
                    Asb + fl*8);
      }
    }
  };

  auto loadB = [&](bf16x8 (&bb)[2][2], int kt) {
    #pragma unroll
    for (int ri = 0; ri < 2; ++ri)
      #pragma unroll
      for (int ks = 0; ks < 2; ++ks)
        bb[ri][ks] = *(const bf16x8*)(wnBase + (size_t)(ri*16) * D_ + kt*64 + ks*32);
  };

  auto computeStep = [&](int sel, const bf16x8 (&bb)[2][2]) {
    unsigned short* Asb = (unsigned short*)(smem + sel*10240);
    #pragma unroll
    for (int ks = 0; ks < 2; ++ks) {
      int swz = ((ks*4 + ksel) ^ (rowsel & 7)) << 3;
      bf16x8 a[5];
      #pragma unroll
      for (int mi = 0; mi < 5; ++mi)
        a[mi] = *(const bf16x8*)(Asb + (mi*16 + rowsel)*64 + swz);
      #pragma unroll
      for (int mi = 0; mi < 5; ++mi)
        #pragma unroll
        for (int ri = 0; ri < 2; ++ri)
          acc[mi][ri] = __builtin_amdgcn_mfma_f32_16x16x32_bf16(a[mi], bb[ri][ks], acc[mi][ri], 0, 0, 0);
    }
  };

  bf16x8 bEven[2][2], bOdd[2][2];
  stageA(0, 0);
  loadB(bEven, 0);
  __syncthreads();                                // A tile 0 + bEven ready
  #pragma unroll 1
  for (int kt = 0; kt < D_/64; kt += 2) {
    if (kt + 1 < D_/64) { stageA(1, (kt+1)*64); loadB(bOdd, kt+1); }
    computeStep(0, bEven);
    __syncthreads();                              // drain stageA(1)+bOdd; buf0 reads done
    if (kt + 2 < D_/64) { stageA(0, (kt+2)*64); loadB(bEven, kt+2); }
    computeStep(1, bOdd);
    __syncthreads();
  }

  // ---- fused epilogue (after final sync; Cl overlaps dead A buffers) ----
  #pragma unroll
  for (int mi = 0; mi < 5; ++mi)
    #pragma unroll
    for (int ri = 0; ri < 2; ++ri)
      #pragma unroll
      for (int rg = 0; rg < 4; ++rg)
        Cl[(mi*16 + ksel*4 + rg)*128 + w*32 + ri*16 + rowsel] = acc[mi][ri][rg];
  for (int i = t; i < 4*N_*K_; i += 256) idxl[i] = nn_idx[b0*N_*K_ + i];
  __syncthreads();

  int bb = w, oo = lane;               // (batch-in-tile, output-in-tile)
  int og = o0 + oo;
  float invv  = gamma[og] / sqrtf(var[og] + BN_EPS);
  float shift = fmaf(-mean[og], invv, beta[og]);
  float bias  = conv_b[og];
  float best = 0.f;                    // relu identity
  int rbase = bb * N_;
  for (int n = 0; n < N_; ++n) {
    float Pv = Cl[(rbase + n)*128 + oo*2];
    float Qn = Cl[(rbase + n)*128 + oo*2 + 1];
    float aa = Pv - Qn + bias;
    const int* ix = idxl + bb*N_*K_ + n*K_;
    #pragma unroll
    for (int kk = 0; kk < K_; ++kk) {
      int j = ix[kk];
      float v = fmaf(aa + Cl[(rbase + j)*128 + oo*2 + 1], invv, shift);
      best = fmaxf(best, v);
    }
  }
  out[(size_t)(b0 + bb) * D_ + og] = best;
}

extern "C" void kernel_launch(void* const* d_in, const int* in_sizes, int n_in,
                              void* d_out, int out_size, void* d_ws, size_t ws_size,
                              hipStream_t stream)
{
  const float* x      = (const float*)d_in[0];
  const float* conv_w = (const float*)d_in[1];
  const float* conv_b = (const float*)d_in[2];
  const float* gamma  = (const float*)d_in[3];
  const float* beta   = (const float*)d_in[4];
  const float* mean   = (const float*)d_in[5];
  const float* var    = (const float*)d_in[6];

  // workspace: nn_idx 76800 B | Xb bf16 7864320 B | Wn bf16 16777216 B  (24.7 MB)
  int* nn_idx = (int*)d_ws;
  unsigned short* Xb = (unsigned short*)((char*)d_ws + 76800);
  unsigned short* Wn = (unsigned short*)((char*)d_ws + 76800 + (size_t)M_*D_*2);

  prep_kernel<<<B_ + 512, 512, 0, stream>>>(x, conv_w, nn_idx, Xb, Wn);
  fused_gemm<<<dim3(24, 32), 256, 0, stream>>>(
      Xb, Wn, nn_idx, conv_b, gamma, beta, mean, var, (float*)d_out);
}